// Round 5
// baseline (300.044 us; speedup 1.0000x reference)
//
#include <hip/hip_runtime.h>

#define HID 256
#define PROJ 256
#define DYN 64
#define HWD 6400
#define BSZ 16
#define NQ 100
#define HH 80
#define WW 80

typedef unsigned short u16;
typedef u16 u16x8 __attribute__((ext_vector_type(8)));
typedef __bf16 bf16x8 __attribute__((ext_vector_type(8)));
typedef float f32x4 __attribute__((ext_vector_type(4)));

__device__ __forceinline__ float bf2f(u16 h) {
    union { unsigned u; float f; } c; c.u = ((unsigned)h) << 16; return c.f;
}
__device__ __forceinline__ u16 f2bf(float f) {
    union { float f; unsigned u; } c; c.f = f;
    return (u16)((c.u + 0x7FFFu + ((c.u >> 16) & 1u)) >> 16);
}

// ---------------------------------------------------------------------------
// K1: per (b, n-chunk of 8): support chain -> fs_feat -> Gt[n][h] -> hi/lo
// bf16 pack in MFMA B-fragment order. Also c[b,n] = bq . fs_feat.
// pack halfword layout: ((((b*2+s)*8 + ks)*8 + nt)*64 + lane)*8 + j
//   value = G_s[h = ks*32 + (lane>>4)*8 + j][n = nt*16 + (lane&15)]
// (unchanged — proven correct)
// ---------------------------------------------------------------------------
__global__ __launch_bounds__(256) void kpre(
    const float* __restrict__ support,   // [100][16][256] f32
    const float* __restrict__ Wq, const float* __restrict__ bq,
    const float* __restrict__ Ws, const float* __restrict__ bsp,
    const float* __restrict__ W1, const float* __restrict__ b1,
    const float* __restrict__ W2, const float* __restrict__ b2,
    u16* __restrict__ pack, float* __restrict__ cvec)
{
    const int c = blockIdx.x;   // n-chunk (8 n each), 0..15
    const int b = blockIdx.y;   // 0..15
    const int t = threadIdx.x;  // 0..255
    const int wv = t >> 6, lane = t & 63;

    __shared__ __align__(16) float sf_t[HID][8];   // support, transposed [i][n]
    __shared__ __align__(16) float fsp[8][PROJ];   // fs_proj [n][p]
    __shared__ __align__(16) float hid[8][DYN];
    __shared__ __align__(16) float fsf_t[PROJ][8]; // fs_feat transposed [p][n]
    __shared__ float cacc[8][4];

    // step 1: load 8 support rows -> transposed LDS
    {
        const int nl = t >> 5;          // 0..7
        const int i0 = (t & 31) * 8;    // 0..248
        const int n = c * 8 + nl;
        float v[8];
        if (n < NQ) {
            const float* sp = support + (size_t)n * (BSZ * HID) + (size_t)b * HID + i0;
            const f32x4 a = *reinterpret_cast<const f32x4*>(sp);
            const f32x4 bb = *reinterpret_cast<const f32x4*>(sp + 4);
            v[0]=a[0]; v[1]=a[1]; v[2]=a[2]; v[3]=a[3];
            v[4]=bb[0]; v[5]=bb[1]; v[6]=bb[2]; v[7]=bb[3];
        } else {
            #pragma unroll
            for (int j = 0; j < 8; ++j) v[j] = 0.f;
        }
        #pragma unroll
        for (int j = 0; j < 8; ++j) sf_t[i0 + j][nl] = v[j];
    }
    __syncthreads();

    // step 2: fs_proj[n][p] = sum_i sf[n][i]*Ws[i][p] + bsp[p]   (thread = p)
    {
        const int p = t;
        float acc[8];
        #pragma unroll
        for (int n = 0; n < 8; ++n) acc[n] = 0.f;
        for (int i = 0; i < HID; ++i) {
            const float w = Ws[(size_t)i * PROJ + p];
            const f32x4 s0 = *reinterpret_cast<const f32x4*>(&sf_t[i][0]);
            const f32x4 s1 = *reinterpret_cast<const f32x4*>(&sf_t[i][4]);
            acc[0] += s0[0] * w; acc[1] += s0[1] * w;
            acc[2] += s0[2] * w; acc[3] += s0[3] * w;
            acc[4] += s1[0] * w; acc[5] += s1[1] * w;
            acc[6] += s1[2] * w; acc[7] += s1[3] * w;
        }
        const float bb = bsp[p];
        #pragma unroll
        for (int n = 0; n < 8; ++n) fsp[n][p] = acc[n] + bb;
    }
    __syncthreads();

    // step 3: hidden[n][d] = relu(fs_proj[n] . W1[:,d] + b1[d])  (wave -> n)
    {
        const int d = lane;
        #pragma unroll
        for (int pass = 0; pass < 2; ++pass) {
            const int nl = pass * 4 + wv;
            float a = 0.f;
            for (int p2 = 0; p2 < PROJ; ++p2)
                a += fsp[nl][p2] * W1[(size_t)p2 * DYN + d];
            a += b1[d];
            hid[nl][d] = a > 0.f ? a : 0.f;
        }
    }
    __syncthreads();

    // step 4: pattern -> fs_feat (transposed), + c partials   (thread = p)
    float cp[8];
    {
        const int p = t;
        const float bqv = bq[p];
        const float b2v = b2[p];
        #pragma unroll
        for (int nl = 0; nl < 8; ++nl) {
            float a = 0.f;
            for (int d = 0; d < DYN; ++d)
                a += hid[nl][d] * W2[(size_t)d * PROJ + p];
            const float pat = tanhf(a + b2v);
            const float ff = (pat + 1.f) * fsp[nl][p];
            fsf_t[p][nl] = ff;
            cp[nl] = bqv * ff;
        }
    }
    __syncthreads();

    // c[b,n] reduction (wave shuffle, then cross-wave)
    #pragma unroll
    for (int nl = 0; nl < 8; ++nl) {
        float v = cp[nl];
        for (int off = 32; off > 0; off >>= 1) v += __shfl_down(v, off);
        if (lane == 0) cacc[nl][wv] = v;
    }
    __syncthreads();
    if (t < 8) {
        const int n = c * 8 + t;
        if (n < NQ) cvec[b * NQ + n] = cacc[t][0] + cacc[t][1] + cacc[t][2] + cacc[t][3];
    }

    // step 5: Gt[n][h] = sum_p Wq[h][p] * fs_feat[n][p]; hi/lo pack  (thread = h)
    {
        const int h = t;
        float acc[8];
        #pragma unroll
        for (int n = 0; n < 8; ++n) acc[n] = 0.f;
        for (int p0 = 0; p0 < PROJ; p0 += 8) {
            const float* wp = Wq + (size_t)h * PROJ + p0;
            const f32x4 w0 = *reinterpret_cast<const f32x4*>(wp);
            const f32x4 w1 = *reinterpret_cast<const f32x4*>(wp + 4);
            float wv8[8] = {w0[0], w0[1], w0[2], w0[3], w1[0], w1[1], w1[2], w1[3]};
            #pragma unroll
            for (int j = 0; j < 8; ++j) {
                const float w = wv8[j];
                const f32x4 f0 = *reinterpret_cast<const f32x4*>(&fsf_t[p0 + j][0]);
                const f32x4 f1 = *reinterpret_cast<const f32x4*>(&fsf_t[p0 + j][4]);
                acc[0] += f0[0] * w; acc[1] += f0[1] * w;
                acc[2] += f0[2] * w; acc[3] += f0[3] * w;
                acc[4] += f1[0] * w; acc[5] += f1[1] * w;
                acc[6] += f1[2] * w; acc[7] += f1[3] * w;
            }
        }
        const int ks = h >> 5, quad = (h >> 3) & 3, j = h & 7;
        const int nt = c >> 1;
        #pragma unroll
        for (int nl = 0; nl < 8; ++nl) {
            const int n = c * 8 + nl;
            const float f = (n < NQ) ? acc[nl] : 0.f;
            const u16 hi = f2bf(f);
            const u16 lo = f2bf(f - bf2f(hi));
            const int nit = (c & 1) * 8 + nl;
            const int lane2 = quad * 16 + nit;
            const size_t base = ((((size_t)b * 2 + 0) * 8 + ks) * 8 + nt) * 512 + lane2 * 8 + j;
            const size_t baseL = base + (size_t)8 * 8 * 512; // s=1 plane
            pack[base] = hi;
            pack[baseL] = lo;
        }
    }
}

// ---------------------------------------------------------------------------
// K2 v3: sim = qf @ G + c via 3-term hi/lo bf16 MFMA.
// Grid (100, 16), 4 waves/block. Wave = 1 m-tile (16 rows) x 7 n-tiles.
// 6400 waves total (grid occupancy cap 78%); VGPR ~100 -> 5 waves/SIMD cap.
// Per K-step: 14 B-loads batched, A for ks+1 prefetched.
// ---------------------------------------------------------------------------
__global__ __launch_bounds__(256) void ksim(
    const float* __restrict__ qf,    // [6400][16][256] f32
    const u16* __restrict__ pack,
    const float* __restrict__ cvec,
    float* __restrict__ sim)         // -> out + 3200, [16][100][6400] f32
{
    const int mc = blockIdx.x;  // 0..99  (64 rows each)
    const int b  = blockIdx.y;  // 0..15
    const int wv = threadIdx.x >> 6;
    const int lane = threadIdx.x & 63;
    const int quad = lane >> 4, l16 = lane & 15;

    f32x4 acc[7];
    #pragma unroll
    for (int nt = 0; nt < 7; ++nt) acc[nt] = (f32x4){0.f, 0.f, 0.f, 0.f};

    const int row = mc * 64 + wv * 16 + l16;
    const float* ap = qf + (size_t)row * (BSZ * HID) + b * HID + quad * 8;
    const u16* pb = pack + (size_t)b * (2 * 8 * 8 * 64 * 8) + (size_t)lane * 8;

    f32x4 a0 = *reinterpret_cast<const f32x4*>(ap + 0);
    f32x4 a1 = *reinterpret_cast<const f32x4*>(ap + 4);

    #pragma unroll
    for (int ks = 0; ks < 8; ++ks) {
        // batch-issue all 14 B loads for this ks
        u16x8 uh[7], ul[7];
        #pragma unroll
        for (int nt = 0; nt < 7; ++nt) {
            uh[nt] = *reinterpret_cast<const u16x8*>(pb + ((size_t)(0 * 8 + ks) * 8 + nt) * 512);
            ul[nt] = *reinterpret_cast<const u16x8*>(pb + ((size_t)(1 * 8 + ks) * 8 + nt) * 512);
        }
        // prefetch A for ks+1
        f32x4 n0, n1;
        if (ks < 7) {
            n0 = *reinterpret_cast<const f32x4*>(ap + (ks + 1) * 32 + 0);
            n1 = *reinterpret_cast<const f32x4*>(ap + (ks + 1) * 32 + 4);
        }
        // convert current A to hi/lo bf16
        bf16x8 ahi, alo;
        #pragma unroll
        for (int j = 0; j < 4; ++j) {
            const float v = a0[j];
            const __bf16 h = (__bf16)v;
            ahi[j] = h; alo[j] = (__bf16)(v - (float)h);
        }
        #pragma unroll
        for (int j = 0; j < 4; ++j) {
            const float v = a1[j];
            const __bf16 h = (__bf16)v;
            ahi[4 + j] = h; alo[4 + j] = (__bf16)(v - (float)h);
        }
        // MFMA block
        #pragma unroll
        for (int nt = 0; nt < 7; ++nt) {
            const bf16x8 bh = __builtin_bit_cast(bf16x8, uh[nt]);
            const bf16x8 bl = __builtin_bit_cast(bf16x8, ul[nt]);
            acc[nt] = __builtin_amdgcn_mfma_f32_16x16x32_bf16(ahi, bh, acc[nt], 0, 0, 0);
            acc[nt] = __builtin_amdgcn_mfma_f32_16x16x32_bf16(ahi, bl, acc[nt], 0, 0, 0);
            acc[nt] = __builtin_amdgcn_mfma_f32_16x16x32_bf16(alo, bh, acc[nt], 0, 0, 0);
        }
        a0 = n0; a1 = n1;
    }

    // epilogue: D row (k-dim) = quad*4 + r, col (n) = l16
    const int kbase = mc * 64 + wv * 16 + quad * 4;
    #pragma unroll
    for (int nt = 0; nt < 7; ++nt) {
        const int n = nt * 16 + l16;
        if (n >= NQ) continue;
        const float cadd = cvec[b * NQ + n];
        f32x4 o = acc[nt];
        o[0] += cadd; o[1] += cadd; o[2] += cadd; o[3] += cadd;
        *reinterpret_cast<f32x4*>(sim + (size_t)(b * NQ + n) * HWD + kbase) = o;
    }
}

// ---------------------------------------------------------------------------
// K3 v4: one 64-thread block (1 wave) per (b,n) row; row held in registers
// (25 x f32x4 per lane). Single global read; no LDS, no barriers.
// ---------------------------------------------------------------------------
__global__ __launch_bounds__(64) void kfin(
    const float* __restrict__ sim,   // out + 3200
    float* __restrict__ out)         // f32 outputs, concatenated
{
    const int bn = blockIdx.x;       // 0..1599
    const int lane = threadIdx.x;    // 0..63
    const float* src = sim + (size_t)bn * HWD;

    // load entire row into registers: lane covers elements j*256 + lane*4 .. +3
    f32x4 v[25];
    #pragma unroll
    for (int j = 0; j < 25; ++j)
        v[j] = *reinterpret_cast<const f32x4*>(src + j * 256 + lane * 4);

    // max / first-occurrence argmax
    float bv = -3.4e38f; int bi = 0;
    #pragma unroll
    for (int j = 0; j < 25; ++j) {
        #pragma unroll
        for (int k = 0; k < 4; ++k) {
            if (v[j][k] > bv) { bv = v[j][k]; bi = j * 256 + lane * 4 + k; }
        }
    }
    #pragma unroll
    for (int m = 1; m < 64; m <<= 1) {
        const float ov = __shfl_xor(bv, m);
        const int oi = __shfl_xor(bi, m);
        if (ov > bv || (ov == bv && oi < bi)) { bv = ov; bi = oi; }
    }
    const int xc = bi % WW, yc = bi / WW;

    // exp sums + 3x3 window sums (from registers)
    float s1 = 0.f, sx = 0.f, sy = 0.f;
    float wl = 0.f, wx = 0.f, wyv = 0.f;
    int x = (lane * 4) % WW, y = (lane * 4) / WW;
    #pragma unroll
    for (int j = 0; j < 25; ++j) {
        #pragma unroll
        for (int k = 0; k < 4; ++k) {
            int xe = x + k, ye = y;
            if (xe >= WW) { xe -= WW; ye += 1; }
            const float e = __expf(v[j][k] - bv);
            const float fx = (float)xe + 0.5f;
            const float fy = (float)ye + 0.5f;
            s1 += e; sx += e * fx; sy += e * fy;
            const int dx = xe - xc, dy = ye - yc;
            const bool inw = (dx >= -1 && dx <= 1 && dy >= -1 && dy <= 1);
            const float ew = inw ? e : 0.f;
            wl += ew; wx += ew * fx; wyv += ew * fy;
        }
        x += 16; y += 3;
        if (x >= WW) { x -= WW; y += 1; }
    }
    #pragma unroll
    for (int m = 1; m < 64; m <<= 1) {
        s1 += __shfl_xor(s1, m);
        sx += __shfl_xor(sx, m);
        sy += __shfl_xor(sy, m);
        wl += __shfl_xor(wl, m);
        wx += __shfl_xor(wx, m);
        wyv += __shfl_xor(wyv, m);
    }

    if (lane == 0) {
        const float invS = 1.f / s1;
        out[(size_t)bn * 2 + 0] = sx * invS / (float)WW;
        out[(size_t)bn * 2 + 1] = sy * invS / (float)HH;
        const float den = wl + 1e-10f * s1;
        const size_t pbase = 3200 + (size_t)BSZ * NQ * HWD;
        out[pbase + (size_t)bn * 2 + 0] = wx / den / (float)WW;
        out[pbase + (size_t)bn * 2 + 1] = wyv / den / (float)HH;
    }
}

extern "C" void kernel_launch(void* const* d_in, const int* in_sizes, int n_in,
                              void* d_out, int out_size, void* d_ws, size_t ws_size,
                              hipStream_t stream) {
    const float* qf  = (const float*)d_in[0];   // query_feat  [6400][16][256] f32
    const float* sf  = (const float*)d_in[1];   // support_feat[100][16][256] f32
    // d_in[2], d_in[3] = h, w (fixed 80x80)
    const float* Wq  = (const float*)d_in[4];
    const float* bq  = (const float*)d_in[5];
    const float* Ws  = (const float*)d_in[6];
    const float* bsp = (const float*)d_in[7];
    const float* W1  = (const float*)d_in[8];
    const float* b1  = (const float*)d_in[9];
    const float* W2  = (const float*)d_in[10];
    const float* b2  = (const float*)d_in[11];

    u16*   pack  = (u16*)d_ws;                         // 2,097,152 B
    float* cvec  = (float*)((char*)d_ws + 2097152);    //     6,400 B
    float* out   = (float*)d_out;
    float* sim   = out + 3200;                         // similarity region, f32

    kpre<<<dim3(16, 16), 256, 0, stream>>>(sf, Wq, bq, Ws, bsp, W1, b1, W2, b2, pack, cvec);
    ksim<<<dim3(100, 16), 256, 0, stream>>>(qf, pack, cvec, sim);
    kfin<<<1600, 64, 0, stream>>>(sim, out);
}

// Round 6
// 277.373 us; speedup vs baseline: 1.0817x; 1.0817x over previous
//
#include <hip/hip_runtime.h>

#define HID 256
#define PROJ 256
#define DYN 64
#define HWD 6400
#define BSZ 16
#define NQ 100
#define HH 80
#define WW 80

typedef unsigned short u16;
typedef u16 u16x8 __attribute__((ext_vector_type(8)));
typedef __bf16 bf16x8 __attribute__((ext_vector_type(8)));
typedef float f32x4 __attribute__((ext_vector_type(4)));

__device__ __forceinline__ float bf2f(u16 h) {
    union { unsigned u; float f; } c; c.u = ((unsigned)h) << 16; return c.f;
}
__device__ __forceinline__ u16 f2bf(float f) {
    union { float f; unsigned u; } c; c.f = f;
    return (u16)((c.u + 0x7FFFu + ((c.u >> 16) & 1u)) >> 16);
}

// ---------------------------------------------------------------------------
// K1: per (b, n-chunk of 8): support chain -> fs_feat -> Gt[n][h] -> hi/lo
// bf16 pack in MFMA B-fragment order. Also c[b,n] = bq . fs_feat.
// launch_bounds(256,1): 1 block/CU (grid=256) -> 512 VGPR cap, so the 8-wide
// load batches in steps 2/3/4 can stay in flight (R5 was serialized at low VGPR).
// ---------------------------------------------------------------------------
__global__ __launch_bounds__(256, 1) void kpre(
    const float* __restrict__ support,   // [100][16][256] f32
    const float* __restrict__ Wq, const float* __restrict__ bq,
    const float* __restrict__ Ws, const float* __restrict__ bsp,
    const float* __restrict__ W1, const float* __restrict__ b1,
    const float* __restrict__ W2, const float* __restrict__ b2,
    u16* __restrict__ pack, float* __restrict__ cvec)
{
    const int c = blockIdx.x;   // n-chunk (8 n each), 0..15
    const int b = blockIdx.y;   // 0..15
    const int t = threadIdx.x;  // 0..255
    const int wv = t >> 6, lane = t & 63;

    __shared__ __align__(16) float sf_t[HID][8];   // support, transposed [i][n]
    __shared__ __align__(16) float fsp[8][PROJ];   // fs_proj [n][p]
    __shared__ __align__(16) float hid[8][DYN];
    __shared__ __align__(16) float fsf_t[PROJ][8]; // fs_feat transposed [p][n]
    __shared__ float cacc[8][4];

    // step 1: load 8 support rows -> transposed LDS
    {
        const int nl = t >> 5;          // 0..7
        const int i0 = (t & 31) * 8;    // 0..248
        const int n = c * 8 + nl;
        float v[8];
        if (n < NQ) {
            const float* sp = support + (size_t)n * (BSZ * HID) + (size_t)b * HID + i0;
            const f32x4 a = *reinterpret_cast<const f32x4*>(sp);
            const f32x4 bb = *reinterpret_cast<const f32x4*>(sp + 4);
            v[0]=a[0]; v[1]=a[1]; v[2]=a[2]; v[3]=a[3];
            v[4]=bb[0]; v[5]=bb[1]; v[6]=bb[2]; v[7]=bb[3];
        } else {
            #pragma unroll
            for (int j = 0; j < 8; ++j) v[j] = 0.f;
        }
        #pragma unroll
        for (int j = 0; j < 8; ++j) sf_t[i0 + j][nl] = v[j];
    }
    __syncthreads();

    // step 2: fs_proj[n][p] = sum_i sf[n][i]*Ws[i][p] + bsp[p]   (thread = p)
    {
        const int p = t;
        float acc[8];
        #pragma unroll
        for (int n = 0; n < 8; ++n) acc[n] = 0.f;
        for (int i0 = 0; i0 < HID; i0 += 8) {
            float w[8];
            #pragma unroll
            for (int j = 0; j < 8; ++j) w[j] = Ws[(size_t)(i0 + j) * PROJ + p];
            #pragma unroll
            for (int j = 0; j < 8; ++j) {
                const f32x4 s0 = *reinterpret_cast<const f32x4*>(&sf_t[i0 + j][0]);
                const f32x4 s1 = *reinterpret_cast<const f32x4*>(&sf_t[i0 + j][4]);
                acc[0] += s0[0] * w[j]; acc[1] += s0[1] * w[j];
                acc[2] += s0[2] * w[j]; acc[3] += s0[3] * w[j];
                acc[4] += s1[0] * w[j]; acc[5] += s1[1] * w[j];
                acc[6] += s1[2] * w[j]; acc[7] += s1[3] * w[j];
            }
        }
        const float bb = bsp[p];
        #pragma unroll
        for (int n = 0; n < 8; ++n) fsp[n][p] = acc[n] + bb;
    }
    __syncthreads();

    // step 3: hidden[n][d] = relu(fs_proj[n] . W1[:,d] + b1[d])  (wave -> n)
    {
        const int d = lane;
        #pragma unroll
        for (int pass = 0; pass < 2; ++pass) {
            const int nl = pass * 4 + wv;
            float a = 0.f;
            for (int p0 = 0; p0 < PROJ; p0 += 8) {
                float w[8];
                #pragma unroll
                for (int j = 0; j < 8; ++j) w[j] = W1[(size_t)(p0 + j) * DYN + d];
                #pragma unroll
                for (int j = 0; j < 8; ++j) a += fsp[nl][p0 + j] * w[j];
            }
            a += b1[d];
            hid[nl][d] = a > 0.f ? a : 0.f;
        }
    }
    __syncthreads();

    // step 4: pattern -> fs_feat (transposed), + c partials   (thread = p)
    float cp[8];
    {
        const int p = t;
        const float bqv = bq[p];
        const float b2v = b2[p];
        float w[8][8];  // W2 column p, all 64 d, batched load
        #pragma unroll
        for (int d0 = 0; d0 < 8; ++d0)
            #pragma unroll
            for (int j = 0; j < 8; ++j) w[d0][j] = W2[(size_t)(d0 * 8 + j) * PROJ + p];
        #pragma unroll
        for (int nl = 0; nl < 8; ++nl) {
            float a = 0.f;
            #pragma unroll
            for (int d0 = 0; d0 < 8; ++d0)
                #pragma unroll
                for (int j = 0; j < 8; ++j) a += hid[nl][d0 * 8 + j] * w[d0][j];
            const float pat = tanhf(a + b2v);
            const float ff = (pat + 1.f) * fsp[nl][p];
            fsf_t[p][nl] = ff;
            cp[nl] = bqv * ff;
        }
    }
    __syncthreads();

    // c[b,n] reduction (wave shuffle, then cross-wave)
    #pragma unroll
    for (int nl = 0; nl < 8; ++nl) {
        float v = cp[nl];
        for (int off = 32; off > 0; off >>= 1) v += __shfl_down(v, off);
        if (lane == 0) cacc[nl][wv] = v;
    }
    __syncthreads();
    if (t < 8) {
        const int n = c * 8 + t;
        if (n < NQ) cvec[b * NQ + n] = cacc[t][0] + cacc[t][1] + cacc[t][2] + cacc[t][3];
    }

    // step 5: Gt[n][h] = sum_p Wq[h][p] * fs_feat[n][p]; hi/lo pack  (thread = h)
    {
        const int h = t;
        float acc[8];
        #pragma unroll
        for (int n = 0; n < 8; ++n) acc[n] = 0.f;
        for (int p0 = 0; p0 < PROJ; p0 += 8) {
            const float* wp = Wq + (size_t)h * PROJ + p0;
            const f32x4 w0 = *reinterpret_cast<const f32x4*>(wp);
            const f32x4 w1 = *reinterpret_cast<const f32x4*>(wp + 4);
            float wv8[8] = {w0[0], w0[1], w0[2], w0[3], w1[0], w1[1], w1[2], w1[3]};
            #pragma unroll
            for (int j = 0; j < 8; ++j) {
                const float w = wv8[j];
                const f32x4 f0 = *reinterpret_cast<const f32x4*>(&fsf_t[p0 + j][0]);
                const f32x4 f1 = *reinterpret_cast<const f32x4*>(&fsf_t[p0 + j][4]);
                acc[0] += f0[0] * w; acc[1] += f0[1] * w;
                acc[2] += f0[2] * w; acc[3] += f0[3] * w;
                acc[4] += f1[0] * w; acc[5] += f1[1] * w;
                acc[6] += f1[2] * w; acc[7] += f1[3] * w;
            }
        }
        const int ks = h >> 5, quad = (h >> 3) & 3, j = h & 7;
        const int nt = c >> 1;
        #pragma unroll
        for (int nl = 0; nl < 8; ++nl) {
            const int n = c * 8 + nl;
            const float f = (n < NQ) ? acc[nl] : 0.f;
            const u16 hi = f2bf(f);
            const u16 lo = f2bf(f - bf2f(hi));
            const int nit = (c & 1) * 8 + nl;
            const int lane2 = quad * 16 + nit;
            const size_t base = ((((size_t)b * 2 + 0) * 8 + ks) * 8 + nt) * 512 + lane2 * 8 + j;
            const size_t baseL = base + (size_t)8 * 8 * 512; // s=1 plane
            pack[base] = hi;
            pack[baseL] = lo;
        }
    }
}

// ---------------------------------------------------------------------------
// K2 v4: same structure as R5, but __launch_bounds__(256, 4): 128 VGPR cap so
// acc(28) + 14 B-frags(56) + A cur/next(16) + hi/lo(8) + addr fit WITHOUT
// serializing the load batch (R5's VGPR=60 forced load->wait->MFMA chains,
// ~8.9k cyc/K-step measured; with batch in flight ~1 L2 latency/K-step).
// ---------------------------------------------------------------------------
__global__ __launch_bounds__(256, 4) void ksim(
    const float* __restrict__ qf,    // [6400][16][256] f32
    const u16* __restrict__ pack,
    const float* __restrict__ cvec,
    float* __restrict__ sim)         // -> out + 3200, [16][100][6400] f32
{
    const int mc = blockIdx.x;  // 0..99  (64 rows each)
    const int b  = blockIdx.y;  // 0..15
    const int wv = threadIdx.x >> 6;
    const int lane = threadIdx.x & 63;
    const int quad = lane >> 4, l16 = lane & 15;

    f32x4 acc[7];
    #pragma unroll
    for (int nt = 0; nt < 7; ++nt) acc[nt] = (f32x4){0.f, 0.f, 0.f, 0.f};

    const int row = mc * 64 + wv * 16 + l16;
    const float* ap = qf + (size_t)row * (BSZ * HID) + b * HID + quad * 8;
    const u16* pb = pack + (size_t)b * (2 * 8 * 8 * 64 * 8) + (size_t)lane * 8;

    f32x4 a0 = *reinterpret_cast<const f32x4*>(ap + 0);
    f32x4 a1 = *reinterpret_cast<const f32x4*>(ap + 4);

    #pragma unroll
    for (int ks = 0; ks < 8; ++ks) {
        // batch-issue all 14 B loads for this ks
        u16x8 uh[7], ul[7];
        #pragma unroll
        for (int nt = 0; nt < 7; ++nt) {
            uh[nt] = *reinterpret_cast<const u16x8*>(pb + ((size_t)(0 * 8 + ks) * 8 + nt) * 512);
            ul[nt] = *reinterpret_cast<const u16x8*>(pb + ((size_t)(1 * 8 + ks) * 8 + nt) * 512);
        }
        // prefetch A for ks+1
        f32x4 n0, n1;
        if (ks < 7) {
            n0 = *reinterpret_cast<const f32x4*>(ap + (ks + 1) * 32 + 0);
            n1 = *reinterpret_cast<const f32x4*>(ap + (ks + 1) * 32 + 4);
        }
        // convert current A to hi/lo bf16
        bf16x8 ahi, alo;
        #pragma unroll
        for (int j = 0; j < 4; ++j) {
            const float v = a0[j];
            const __bf16 h = (__bf16)v;
            ahi[j] = h; alo[j] = (__bf16)(v - (float)h);
        }
        #pragma unroll
        for (int j = 0; j < 4; ++j) {
            const float v = a1[j];
            const __bf16 h = (__bf16)v;
            ahi[4 + j] = h; alo[4 + j] = (__bf16)(v - (float)h);
        }
        // MFMA block
        #pragma unroll
        for (int nt = 0; nt < 7; ++nt) {
            const bf16x8 bh = __builtin_bit_cast(bf16x8, uh[nt]);
            const bf16x8 bl = __builtin_bit_cast(bf16x8, ul[nt]);
            acc[nt] = __builtin_amdgcn_mfma_f32_16x16x32_bf16(ahi, bh, acc[nt], 0, 0, 0);
            acc[nt] = __builtin_amdgcn_mfma_f32_16x16x32_bf16(ahi, bl, acc[nt], 0, 0, 0);
            acc[nt] = __builtin_amdgcn_mfma_f32_16x16x32_bf16(alo, bh, acc[nt], 0, 0, 0);
        }
        a0 = n0; a1 = n1;
    }

    // epilogue: D row (k-dim) = quad*4 + r, col (n) = l16
    const int kbase = mc * 64 + wv * 16 + quad * 4;
    #pragma unroll
    for (int nt = 0; nt < 7; ++nt) {
        const int n = nt * 16 + l16;
        if (n >= NQ) continue;
        const float cadd = cvec[b * NQ + n];
        f32x4 o = acc[nt];
        o[0] += cadd; o[1] += cadd; o[2] += cadd; o[3] += cadd;
        *reinterpret_cast<f32x4*>(sim + (size_t)(b * NQ + n) * HWD + kbase) = o;
    }
}

// ---------------------------------------------------------------------------
// K3 v5: one wave per (b,n) row; row in registers (25 x f32x4/lane = 100 VGPR).
// __launch_bounds__(64, 4): 128 VGPR cap so all 25 loads stay in flight.
// ---------------------------------------------------------------------------
__global__ __launch_bounds__(64, 4) void kfin(
    const float* __restrict__ sim,   // out + 3200
    float* __restrict__ out)         // f32 outputs, concatenated
{
    const int bn = blockIdx.x;       // 0..1599
    const int lane = threadIdx.x;    // 0..63
    const float* src = sim + (size_t)bn * HWD;

    // load entire row into registers: lane covers elements j*256 + lane*4 .. +3
    f32x4 v[25];
    #pragma unroll
    for (int j = 0; j < 25; ++j)
        v[j] = *reinterpret_cast<const f32x4*>(src + j * 256 + lane * 4);

    // max / first-occurrence argmax
    float bv = -3.4e38f; int bi = 0;
    #pragma unroll
    for (int j = 0; j < 25; ++j) {
        #pragma unroll
        for (int k = 0; k < 4; ++k) {
            if (v[j][k] > bv) { bv = v[j][k]; bi = j * 256 + lane * 4 + k; }
        }
    }
    #pragma unroll
    for (int m = 1; m < 64; m <<= 1) {
        const float ov = __shfl_xor(bv, m);
        const int oi = __shfl_xor(bi, m);
        if (ov > bv || (ov == bv && oi < bi)) { bv = ov; bi = oi; }
    }
    const int xc = bi % WW, yc = bi / WW;

    // exp sums + 3x3 window sums (from registers)
    float s1 = 0.f, sx = 0.f, sy = 0.f;
    float wl = 0.f, wx = 0.f, wyv = 0.f;
    int x = (lane * 4) % WW, y = (lane * 4) / WW;
    #pragma unroll
    for (int j = 0; j < 25; ++j) {
        #pragma unroll
        for (int k = 0; k < 4; ++k) {
            int xe = x + k, ye = y;
            if (xe >= WW) { xe -= WW; ye += 1; }
            const float e = __expf(v[j][k] - bv);
            const float fx = (float)xe + 0.5f;
            const float fy = (float)ye + 0.5f;
            s1 += e; sx += e * fx; sy += e * fy;
            const int dx = xe - xc, dy = ye - yc;
            const bool inw = (dx >= -1 && dx <= 1 && dy >= -1 && dy <= 1);
            const float ew = inw ? e : 0.f;
            wl += ew; wx += ew * fx; wyv += ew * fy;
        }
        x += 16; y += 3;
        if (x >= WW) { x -= WW; y += 1; }
    }
    #pragma unroll
    for (int m = 1; m < 64; m <<= 1) {
        s1 += __shfl_xor(s1, m);
        sx += __shfl_xor(sx, m);
        sy += __shfl_xor(sy, m);
        wl += __shfl_xor(wl, m);
        wx += __shfl_xor(wx, m);
        wyv += __shfl_xor(wyv, m);
    }

    if (lane == 0) {
        const float invS = 1.f / s1;
        out[(size_t)bn * 2 + 0] = sx * invS / (float)WW;
        out[(size_t)bn * 2 + 1] = sy * invS / (float)HH;
        const float den = wl + 1e-10f * s1;
        const size_t pbase = 3200 + (size_t)BSZ * NQ * HWD;
        out[pbase + (size_t)bn * 2 + 0] = wx / den / (float)WW;
        out[pbase + (size_t)bn * 2 + 1] = wyv / den / (float)HH;
    }
}

extern "C" void kernel_launch(void* const* d_in, const int* in_sizes, int n_in,
                              void* d_out, int out_size, void* d_ws, size_t ws_size,
                              hipStream_t stream) {
    const float* qf  = (const float*)d_in[0];   // query_feat  [6400][16][256] f32
    const float* sf  = (const float*)d_in[1];   // support_feat[100][16][256] f32
    // d_in[2], d_in[3] = h, w (fixed 80x80)
    const float* Wq  = (const float*)d_in[4];
    const float* bq  = (const float*)d_in[5];
    const float* Ws  = (const float*)d_in[6];
    const float* bsp = (const float*)d_in[7];
    const float* W1  = (const float*)d_in[8];
    const float* b1  = (const float*)d_in[9];
    const float* W2  = (const float*)d_in[10];
    const float* b2  = (const float*)d_in[11];

    u16*   pack  = (u16*)d_ws;                         // 2,097,152 B
    float* cvec  = (float*)((char*)d_ws + 2097152);    //     6,400 B
    float* out   = (float*)d_out;
    float* sim   = out + 3200;                         // similarity region, f32

    kpre<<<dim3(16, 16), 256, 0, stream>>>(sf, Wq, bq, Ws, bsp, W1, b1, W2, b2, pack, cvec);
    ksim<<<dim3(100, 16), 256, 0, stream>>>(qf, pack, cvec, sim);
    kfin<<<1600, 64, 0, stream>>>(sim, out);
}